// Round 5
// baseline (49.835 us; speedup 1.0000x reference)
//
#include <hip/hip_runtime.h>
#include <math.h>

#define EPS_CLIP 1e-6f
#define WPB 8      // b's per wave (contiguous 18.4 KB stream per wave)
#define NWAVES 4   // waves per block

struct F3 { float x, y, z; };   // 12 B, 4-B aligned -> dwordx3

// SS = compile-time S (0 -> runtime S_rt)
template <int SS>
__global__ __launch_bounds__(256) void sym_loss_kernel(
    const float* __restrict__ R_pred,   // (B, 64, 3, 3)
    const float* __restrict__ R_gt,     // (B, 3, 3)
    const float* __restrict__ rot,      // (S, 3, 3)
    float* __restrict__ partial,        // (gridDim.x,)
    unsigned int* __restrict__ counter, // zeroed by memsetAsync each call
    float* __restrict__ out,
    int S_rt, float invB)
{
    const int S    = SS ? SS : S_rt;
    const int tid  = threadIdx.x;
    const int lane = tid & 63;
    const int wid  = tid >> 6;
    const int gw   = __builtin_amdgcn_readfirstlane(blockIdx.x * NWAVES + wid);
    const int b0   = gw * WPB;

    // ---- issue ALL 24 dwordx3 loads upfront: 864 B/lane-wave in flight ----
    F3 A[WPB][3];
    #pragma unroll
    for (int k = 0; k < WPB; ++k) {
        const F3* src = reinterpret_cast<const F3*>(R_pred + ((size_t)(b0 + k) * 64 + lane) * 9);
        A[k][0] = src[0]; A[k][1] = src[1]; A[k][2] = src[2];
    }

    float mk[WPB];
    #pragma unroll
    for (int k = 0; k < WPB; ++k) {
        const int b = b0 + k;   // wave-uniform

        // G: wave-uniform address -> scalar loads
        const float* G = R_gt + (size_t)b * 9;
        float g[9];
        #pragma unroll
        for (int e = 0; e < 9; ++e) g[e] = G[e];

        const float p[9] = { A[k][0].x, A[k][0].y, A[k][0].z,
                             A[k][1].x, A[k][1].y, A[k][1].z,
                             A[k][2].x, A[k][2].y, A[k][2].z };

        // Q = P * G^T (27 FMA);  trace(P @ (rot_s @ G)^T) = <Q, rot_s>  (cyclic trace)
        float q[9];
        #pragma unroll
        for (int i = 0; i < 3; ++i)
            #pragma unroll
            for (int j = 0; j < 3; ++j)
                q[i * 3 + j] = fmaf(p[i * 3 + 0], g[j * 3 + 0],
                               fmaf(p[i * 3 + 1], g[j * 3 + 1],
                                    p[i * 3 + 2] * g[j * 3 + 2]));

        // S trace-dots against rot (grid-uniform -> SGPRs)
        float m = -1e30f;
        if (SS) {
            #pragma unroll
            for (int s = 0; s < SS; ++s) {
                const float* Rs = rot + s * 9;
                float tr = 0.f;
                #pragma unroll
                for (int e = 0; e < 9; ++e) tr = fmaf(q[e], Rs[e], tr);
                m = fmaxf(m, tr);
            }
        } else {
            for (int s = 0; s < S; ++s) {
                const float* Rs = rot + s * 9;
                float tr = 0.f;
                #pragma unroll
                for (int e = 0; e < 9; ++e) tr = fmaf(q[e], Rs[e], tr);
                m = fmaxf(m, tr);
            }
        }

        // max over the 64 candidate lanes
        #pragma unroll
        for (int off = 32; off; off >>= 1) m = fmaxf(m, __shfl_xor(m, off));
        mk[k] = m;   // every lane holds the wave max
    }

    // ---- batched acos: lanes 0..WPB-1 each take one of the 8 maxes ----
    float mv = mk[0];
    #pragma unroll
    for (int k = 1; k < WPB; ++k) mv = (lane == k) ? mk[k] : mv;
    float cosv = (mv - 1.0f) * 0.5f;
    cosv = fminf(fmaxf(cosv, -1.0f + EPS_CLIP), 1.0f - EPS_CLIP);
    float a = (lane < WPB) ? acosf(cosv) : 0.0f;   // min over (c,s) of arccos == arccos of max
    #pragma unroll
    for (int off = 1; off < WPB; off <<= 1) a += __shfl_xor(a, off);

    __shared__ float sLoss[NWAVES];
    if (lane == 0) sLoss[wid] = a;
    __syncthreads();

    // ---- fused grid reduction: last-block-done pattern (deterministic) ----
    if (tid == 0) {
        float bsum = 0.f;
        #pragma unroll
        for (int i = 0; i < NWAVES; ++i) bsum += sLoss[i];
        __hip_atomic_store(&partial[blockIdx.x], bsum,
                           __ATOMIC_RELAXED, __HIP_MEMORY_SCOPE_AGENT);
        unsigned prev = __hip_atomic_fetch_add(counter, 1u,
                           __ATOMIC_ACQ_REL, __HIP_MEMORY_SCOPE_AGENT);
        sLoss[0] = (prev == gridDim.x - 1) ? 1.0f : 0.0f;
    }
    __syncthreads();

    if (sLoss[0] != 0.0f) {     // last block only: fixed-order reduce of all partials
        const int n = gridDim.x;
        float sum = 0.f;
        for (int i = tid; i < n; i += 256)
            sum += __hip_atomic_load(&partial[i],
                       __ATOMIC_RELAXED, __HIP_MEMORY_SCOPE_AGENT);
        #pragma unroll
        for (int off = 32; off; off >>= 1) sum += __shfl_xor(sum, off);
        __shared__ float ws[NWAVES];
        if (lane == 0) ws[wid] = sum;
        __syncthreads();
        if (tid == 0) {
            float t = 0.f;
            #pragma unroll
            for (int i = 0; i < NWAVES; ++i) t += ws[i];
            out[0] = t * invB;
        }
    }
}

extern "C" void kernel_launch(void* const* d_in, const int* in_sizes, int n_in,
                              void* d_out, int out_size, void* d_ws, size_t ws_size,
                              hipStream_t stream) {
    const float* R_pred = (const float*)d_in[0];
    const float* R_gt   = (const float*)d_in[1];
    const float* rot    = (const float*)d_in[2];
    float* out = (float*)d_out;

    const int B = in_sizes[1] / 9;                 // 32768
    const int S = in_sizes[2] / 9;                 // 12
    const int nBlocks = B / (WPB * NWAVES);        // 1024

    float* partial = (float*)d_ws;                            // nBlocks floats
    unsigned* counter = (unsigned*)((char*)d_ws + (size_t)nBlocks * sizeof(float));

    hipMemsetAsync(counter, 0, sizeof(unsigned), stream);     // stream-ordered, capturable

    if (S == 12)
        sym_loss_kernel<12><<<nBlocks, 256, 0, stream>>>(
            R_pred, R_gt, rot, partial, counter, out, S, 1.0f / (float)B);
    else
        sym_loss_kernel<0><<<nBlocks, 256, 0, stream>>>(
            R_pred, R_gt, rot, partial, counter, out, S, 1.0f / (float)B);
}

// Round 6
// 21.526 us; speedup vs baseline: 2.3152x; 2.3152x over previous
//
#include <hip/hip_runtime.h>
#include <math.h>

#define EPS_CLIP 1e-6f
#define WPB 4      // b's per wave
#define NWAVES 4   // waves per block

struct F3 { float x, y, z; };   // 12 B -> global_load_dwordx3

// SS = compile-time S (0 -> runtime S_rt)
template <int SS>
__global__ __launch_bounds__(256) void sym_loss_kernel(
    const float* __restrict__ R_pred,   // (B, 64, 3, 3)
    const float* __restrict__ R_gt,     // (B, 3, 3)
    const float* __restrict__ rot,      // (S, 3, 3)
    float* __restrict__ partial,        // (gridDim.x,)
    int S_rt)
{
    const int S    = SS ? SS : S_rt;
    const int tid  = threadIdx.x;
    const int lane = tid & 63;
    const int wid  = tid >> 6;
    const int gw   = __builtin_amdgcn_readfirstlane(blockIdx.x * NWAVES + wid);
    const int b0   = gw * WPB;

    // per-lane base: candidate `lane` of rotation b0 (3 F3 rows); next b = +192 F3
    const F3* base = reinterpret_cast<const F3*>(R_pred) + ((size_t)b0 * 64 + lane) * 3;

    // ---- 3-slot register ring, prefetch distance 2 (72 B/lane in flight) ----
    F3 A[3][3];
    #pragma unroll
    for (int r = 0; r < 3; ++r) A[0][r] = base[r];
    #pragma unroll
    for (int r = 0; r < 3; ++r) A[1][r] = base[192 + r];

    float mk[WPB];
    #pragma unroll
    for (int k = 0; k < WPB; ++k) {
        // issue load for k+2 before computing k
        if (k + 2 < WPB) {
            #pragma unroll
            for (int r = 0; r < 3; ++r)
                A[(k + 2) % 3][r] = base[(size_t)(k + 2) * 192 + r];
        }
        const int slot = k % 3;       // compile-time after unroll
        const int b = b0 + k;         // wave-uniform

        // G: wave-uniform address -> scalar loads
        const float* G = R_gt + (size_t)b * 9;
        float g[9];
        #pragma unroll
        for (int e = 0; e < 9; ++e) g[e] = G[e];

        const float p[9] = { A[slot][0].x, A[slot][0].y, A[slot][0].z,
                             A[slot][1].x, A[slot][1].y, A[slot][1].z,
                             A[slot][2].x, A[slot][2].y, A[slot][2].z };

        // Q = P * G^T (27 FMA);  trace(P @ (rot_s @ G)^T) = <Q, rot_s>  (cyclic trace)
        float q[9];
        #pragma unroll
        for (int i = 0; i < 3; ++i)
            #pragma unroll
            for (int j = 0; j < 3; ++j)
                q[i * 3 + j] = fmaf(p[i * 3 + 0], g[j * 3 + 0],
                               fmaf(p[i * 3 + 1], g[j * 3 + 1],
                                    p[i * 3 + 2] * g[j * 3 + 2]));

        // S trace-dots against rot (grid-uniform -> SGPRs)
        float m = -1e30f;
        if (SS) {
            #pragma unroll
            for (int s = 0; s < SS; ++s) {
                const float* Rs = rot + s * 9;
                float tr = 0.f;
                #pragma unroll
                for (int e = 0; e < 9; ++e) tr = fmaf(q[e], Rs[e], tr);
                m = fmaxf(m, tr);
            }
        } else {
            for (int s = 0; s < S; ++s) {
                const float* Rs = rot + s * 9;
                float tr = 0.f;
                #pragma unroll
                for (int e = 0; e < 9; ++e) tr = fmaf(q[e], Rs[e], tr);
                m = fmaxf(m, tr);
            }
        }

        // max over the 64 candidate lanes
        #pragma unroll
        for (int off = 32; off; off >>= 1) m = fmaxf(m, __shfl_xor(m, off));
        mk[k] = m;   // every lane holds the wave max
    }

    // ---- batched acos: lanes 0..3 each take one wave max, single acosf ----
    float mv = mk[0];
    #pragma unroll
    for (int k = 1; k < WPB; ++k) mv = (lane == k) ? mk[k] : mv;
    float cosv = (mv - 1.0f) * 0.5f;
    cosv = fminf(fmaxf(cosv, -1.0f + EPS_CLIP), 1.0f - EPS_CLIP);
    float a = (lane < WPB) ? acosf(cosv) : 0.0f;  // min over (c,s) arccos == arccos(max trace)
    a += __shfl_xor(a, 1);
    a += __shfl_xor(a, 2);

    __shared__ float sLoss[NWAVES];
    if (lane == 0) sLoss[wid] = a;
    __syncthreads();
    if (tid == 0) {
        float sum = 0.f;
        #pragma unroll
        for (int i = 0; i < NWAVES; ++i) sum += sLoss[i];
        partial[blockIdx.x] = sum;
    }
}

__global__ __launch_bounds__(1024) void reduce_kernel(
    const float* __restrict__ partial, int n, float* __restrict__ out, float invB)
{
    float sum = 0.f;
    for (int i = threadIdx.x; i < n; i += 1024) sum += partial[i];
    #pragma unroll
    for (int off = 32; off; off >>= 1) sum += __shfl_xor(sum, off);
    __shared__ float ws[16];
    const int w = threadIdx.x >> 6;
    if ((threadIdx.x & 63) == 0) ws[w] = sum;
    __syncthreads();
    if (threadIdx.x == 0) {
        float t = 0.f;
        #pragma unroll
        for (int i = 0; i < 16; ++i) t += ws[i];
        out[0] = t * invB;
    }
}

extern "C" void kernel_launch(void* const* d_in, const int* in_sizes, int n_in,
                              void* d_out, int out_size, void* d_ws, size_t ws_size,
                              hipStream_t stream) {
    const float* R_pred = (const float*)d_in[0];
    const float* R_gt   = (const float*)d_in[1];
    const float* rot    = (const float*)d_in[2];
    float* out = (float*)d_out;

    const int B = in_sizes[1] / 9;                 // 32768
    const int S = in_sizes[2] / 9;                 // 12
    const int nBlocks = B / (WPB * NWAVES);        // 2048

    float* partial = (float*)d_ws;                 // nBlocks * 4 B

    if (S == 12)
        sym_loss_kernel<12><<<nBlocks, 256, 0, stream>>>(R_pred, R_gt, rot, partial, S);
    else
        sym_loss_kernel<0><<<nBlocks, 256, 0, stream>>>(R_pred, R_gt, rot, partial, S);

    reduce_kernel<<<1, 1024, 0, stream>>>(partial, nBlocks, out, 1.0f / (float)B);
}